// Round 8
// baseline (3554.021 us; speedup 1.0000x reference)
//
#include <hip/hip_runtime.h>
#include <hip/hip_bf16.h>

// NCA2D: B=16, H=128, W=128, C=16, T=8, HID=128, N_STEPS=64, FC0_IN=49
constexpr int B = 16, H = 128, W = 128, C = 16, T = 8, HID = 128, NSTEPS = 64;

using f32x4  = __attribute__((ext_vector_type(4))) float;
using bf16x8 = __attribute__((ext_vector_type(8))) short;

__device__ __forceinline__ unsigned short bf16_hi(float v) {
    __hip_bfloat16 h = __float2bfloat16(v);
    return *reinterpret_cast<unsigned short*>(&h);
}
__device__ __forceinline__ float bf16_f32(unsigned short u) {
    union { unsigned int u; float f; } c; c.u = ((unsigned int)u) << 16; return c.f;
}

// Packed fragment table (40 rows x 64 lanes x 16B = 40KB):
//  rows 0..31 : fc0 B-frags, row = nt*4 + f, f in {b0h,b0l,b1h,b1l}
//  rows 32..39: fc1 A-frags (W1), row = 32 + ks*2 + f, f in {hi,lo}
__global__ void prep_pack(const float* __restrict__ fc0_w, const float* __restrict__ fc1_w,
                          unsigned short* __restrict__ pack) {
    for (int e = threadIdx.x; e < 40 * 64; e += 256) {
        const int row = e >> 6, l = e & 63;
        const int m = l & 15, g = l >> 4;
        unsigned short v[8];
        if (row < 32) {
            const int nt = row >> 2, f = row & 3;
            const int n = nt * 16 + m;
            const int kbase = ((f >= 2) ? 32 : 0) + g * 8;
            #pragma unroll
            for (int j = 0; j < 8; ++j) {
                const int k = kbase + j;
                const float x = (k < 49) ? fc0_w[n * 49 + k] : 0.0f;
                const unsigned short hi = bf16_hi(x);
                v[j] = (f & 1) ? bf16_hi(x - bf16_f32(hi)) : hi;
            }
        } else {
            const int rr = row - 32, ks = rr >> 1, f = rr & 1;
            #pragma unroll
            for (int j = 0; j < 8; ++j) {
                const float x = fc1_w[m * HID + ks * 32 + g * 8 + j];
                const unsigned short hi = bf16_hi(x);
                v[j] = f ? bf16_hi(x - bf16_f32(hi)) : hi;
            }
        }
        #pragma unroll
        for (int j = 0; j < 8; ++j) pack[e * 8 + j] = v[j];
    }
}

// Zero only output slots whose acquire step is 0 (never snapshot-written).
__global__ void zero_acq0(const int* __restrict__ acq, float* __restrict__ out) {
    const int bt = blockIdx.x;
    if (acq[bt] != 0) return;
    float4* p = reinterpret_cast<float4*>(out + (size_t)bt * (H * W * C));
    for (int i = threadIdx.x; i < (H * W * C) / 4; i += 256)
        p[i] = make_float4(0.0f, 0.0f, 0.0f, 0.0f);
}

// 4 waves/block, 4 tiles/block. LDS 64KB -> 2 blocks/CU. Conv loads for tile t+1
// are issued right after tile t's conv consumes its buffer, hiding global latency
// under tile t's MFMA phase. fc0 uses two independent 3-MFMA chains, fc1 two
// independent 6-MFMA chains (dependent-latency hiding at 2 waves/SIMD).
__global__ __launch_bounds__(256, 2) void nca_step(
    const float* __restrict__ x_in, float* __restrict__ x_out,
    const float* __restrict__ p0_w, const float* __restrict__ p0_b,
    const float* __restrict__ p1_w, const float* __restrict__ p1_b,
    const unsigned short* __restrict__ pack, const float* __restrict__ fc0_b,
    const int* __restrict__ acq, float* __restrict__ out, int step)
{
    __shared__ float wlds[32 * 256];   // fc0 B-frag rows
    __shared__ float hlds[4 * 2048];   // per-wave h[16][128], 16B-XOR swizzle

    const int tid  = threadIdx.x;
    const int wv   = tid >> 6;
    const int lane = tid & 63;
    const int m    = lane & 15;
    const int g    = lane >> 4;

    // ---- stage fc0 frag table global->LDS
    #pragma unroll
    for (int e0 = 0; e0 < 2048; e0 += 256) {
        const int e = e0 + tid;
        const int4 v = *reinterpret_cast<const int4*>(pack + (size_t)e * 8);
        *reinterpret_cast<int4*>(&wlds[e * 4]) = v;
    }

    const int blockbase = blockIdx.x * 256;
    const int b = blockbase >> 14;

    const float* pw = (g >= 2) ? p0_w : p1_w;
    const float* pb = (g >= 2) ? p0_b : p1_b;
    const int ch = (g & 1) * 8;
    float* hb = hlds + (wv << 11);
    const int lb = lane << 2;
    const int m7 = m & 7;
    const float prog = (float)step * (1.0f / (float)NSTEPS);

    // ---- block-invariant loads
    int snapmask = 0;
    if (step > 0) {
        #pragma unroll
        for (int t = 0; t < T; ++t)
            snapmask |= (acq[b * T + t] == step) ? (1 << t) : 0;
    }
    bf16x8 w1f[8];
    #pragma unroll
    for (int q = 0; q < 8; ++q)
        w1f[q] = *reinterpret_cast<const bf16x8*>(pack + ((32 + q) * 64 + lane) * 8);
    float bias[8];
    #pragma unroll
    for (int nt = 0; nt < 8; ++nt) bias[nt] = fc0_b[nt * 16 + m];

    // ---- conv-load prefetch buffers (double-buffered across tiles)
    float4 cva[2][9], cvb[2][9], xo4[2];

    auto issue_tile = [&](int tt) {
        const int par = tt & 1;
        const int cb = blockbase + tt * 64 + wv * 16;
        const int hr = (cb >> 7) & (H - 1);
        const int wb = cb & (W - 1);
        const int wc = wb + m;
        int hs[3], ws[3];
        hs[0] = (hr == 0) ? 1 : hr - 1;  hs[1] = hr;  hs[2] = (hr == H - 1) ? H - 2 : hr + 1;
        ws[0] = (wc == 0) ? 1 : wc - 1;  ws[1] = wc;  ws[2] = (wc == W - 1) ? W - 2 : wc + 1;
        #pragma unroll
        for (int i = 0; i < 3; ++i) {
            #pragma unroll
            for (int j = 0; j < 3; ++j) {
                const float4* p4 = reinterpret_cast<const float4*>(
                    x_in + (((size_t)(b * H + hs[i]) * W + ws[j]) << 4) + ch);
                cva[par][i * 3 + j] = p4[0];
                cvb[par][i * 3 + j] = p4[1];
            }
        }
        xo4[par] = *reinterpret_cast<const float4*>(
            x_in + ((size_t)(cb + m) << 4) + (g << 2));
    };

    issue_tile(0);

    #pragma unroll
    for (int t = 0; t < 4; ++t) {
        const int par = t & 1;
        const int cellbase = blockbase + t * 64 + wv * 16;
        const int hrow  = (cellbase >> 7) & (H - 1);
        const int wbase = cellbase & (W - 1);

        // ---- conv FMAs from prefetched registers
        float z[8], xcen[8];
        #pragma unroll
        for (int j = 0; j < 8; ++j) z[j] = pb[ch + j];
        #pragma unroll
        for (int p = 0; p < 9; ++p) {
            const float4 qa = cva[par][p], qb = cvb[par][p];
            const float xv[8] = {qa.x, qa.y, qa.z, qa.w, qb.x, qb.y, qb.z, qb.w};
            #pragma unroll
            for (int j = 0; j < 8; ++j)
                z[j] = fmaf(xv[j], pw[p * 16 + ch + j], z[j]);
            if (p == 4) {
                #pragma unroll
                for (int j = 0; j < 8; ++j) xcen[j] = xv[j];
            }
        }
        const float4 xold4 = xo4[par];

        // ---- prefetch next tile's conv inputs (latency hides under fc0/fc1)
        if (t < 3) issue_tile(t + 1);

        // ---- A-frags (K=64: k0-31 = [x | z1], k32-63 = [z2 | prog | pad])
        bf16x8 a0h, a0l, a1h, a1l;
        #pragma unroll
        for (int j = 0; j < 8; ++j) {
            const float f0 = (g < 2) ? xcen[j] : z[j];
            const float f1 = (g < 2) ? z[j] : ((g == 2 && j == 0) ? prog : 0.0f);
            const unsigned short h0 = bf16_hi(f0);
            a0h[j] = (short)h0;  a0l[j] = (short)bf16_hi(f0 - bf16_f32(h0));
            const unsigned short h1 = bf16_hi(f1);
            a1h[j] = (short)h1;  a1l[j] = (short)bf16_hi(f1 - bf16_f32(h1));
        }

        if (t == 0) __syncthreads();   // staged wlds visible (uniform branch)

        // ---- fc0: two independent 3-chains per nt (accL: k0-31, accH: k32-63)
        #pragma unroll
        for (int nt = 0; nt < 8; ++nt) {
            const int rb = nt << 10;
            const bf16x8 b0h = *reinterpret_cast<const bf16x8*>(&wlds[rb + lb]);
            const bf16x8 b0l = *reinterpret_cast<const bf16x8*>(&wlds[rb + 256 + lb]);
            const bf16x8 b1h = *reinterpret_cast<const bf16x8*>(&wlds[rb + 512 + lb]);
            const bf16x8 b1l = *reinterpret_cast<const bf16x8*>(&wlds[rb + 768 + lb]);
            f32x4 accL = {0.0f, 0.0f, 0.0f, 0.0f};
            f32x4 accH = {0.0f, 0.0f, 0.0f, 0.0f};
            accL = __builtin_amdgcn_mfma_f32_16x16x32_bf16(a0h, b0h, accL, 0, 0, 0);
            accH = __builtin_amdgcn_mfma_f32_16x16x32_bf16(a1h, b1h, accH, 0, 0, 0);
            accL = __builtin_amdgcn_mfma_f32_16x16x32_bf16(a0l, b0h, accL, 0, 0, 0);
            accH = __builtin_amdgcn_mfma_f32_16x16x32_bf16(a1l, b1h, accH, 0, 0, 0);
            accL = __builtin_amdgcn_mfma_f32_16x16x32_bf16(a0h, b0l, accL, 0, 0, 0);
            accH = __builtin_amdgcn_mfma_f32_16x16x32_bf16(a1h, b1l, accH, 0, 0, 0);
            const int hid4 = (nt << 2) + (m >> 2), ml = m & 3;
            #pragma unroll
            for (int r = 0; r < 4; ++r) {
                const int cr = g * 4 + r;
                hb[cr * 128 + (((hid4 ^ (cr & 7)) << 2) | ml)] =
                    fmaxf(accL[r] + accH[r] + bias[nt], 0.0f);
            }
        }
        // no block barrier: hlds is wave-private, within-wave DS ordering suffices

        // ---- fc1 swapped (D2 = W1 . h^T): two independent 6-chains
        f32x4 acc2a = {0.0f, 0.0f, 0.0f, 0.0f};
        f32x4 acc2b = {0.0f, 0.0f, 0.0f, 0.0f};
        #pragma unroll
        for (int ks = 0; ks < 4; ++ks) {
            const float4 h0 = *reinterpret_cast<const float4*>(
                &hb[m * 128 + ((((ks << 3) + (g << 1) + 0) ^ m7) << 2)]);
            const float4 h1 = *reinterpret_cast<const float4*>(
                &hb[m * 128 + ((((ks << 3) + (g << 1) + 1) ^ m7) << 2)]);
            const float hv[8] = {h0.x, h0.y, h0.z, h0.w, h1.x, h1.y, h1.z, h1.w};
            bf16x8 bh, bl;
            #pragma unroll
            for (int j = 0; j < 8; ++j) {
                const unsigned short hi = bf16_hi(hv[j]);
                bh[j] = (short)hi;
                bl[j] = (short)bf16_hi(hv[j] - bf16_f32(hi));
            }
            f32x4& acc2 = (ks & 1) ? acc2b : acc2a;
            acc2 = __builtin_amdgcn_mfma_f32_16x16x32_bf16(w1f[ks * 2 + 0], bh, acc2, 0, 0, 0);
            acc2 = __builtin_amdgcn_mfma_f32_16x16x32_bf16(w1f[ks * 2 + 1], bh, acc2, 0, 0, 0);
            acc2 = __builtin_amdgcn_mfma_f32_16x16x32_bf16(w1f[ks * 2 + 0], bl, acc2, 0, 0, 0);
        }

        // ---- epilogue
        const size_t cell = (size_t)(cellbase + m);
        float4 xn;
        xn.x = xold4.x + 1.0f / (1.0f + __expf(-(acc2a[0] + acc2b[0])));
        xn.y = xold4.y + 1.0f / (1.0f + __expf(-(acc2a[1] + acc2b[1])));
        xn.z = xold4.z + 1.0f / (1.0f + __expf(-(acc2a[2] + acc2b[2])));
        xn.w = xold4.w + 1.0f / (1.0f + __expf(-(acc2a[3] + acc2b[3])));
        *reinterpret_cast<float4*>(x_out + (cell << 4) + g * 4) = xn;
        if (snapmask) {
            #pragma unroll
            for (int tt = 0; tt < T; ++tt) {
                if (snapmask & (1 << tt)) {
                    *reinterpret_cast<float4*>(out + (size_t)(b * T + tt) * (H * W * C)
                        + (((size_t)hrow * W + wbase + m) << 4) + g * 4) = xn;
                }
            }
        }
    }
}

extern "C" void kernel_launch(void* const* d_in, const int* in_sizes, int n_in,
                              void* d_out, int out_size, void* d_ws, size_t ws_size,
                              hipStream_t stream) {
    const float* inputs = (const float*)d_in[0];
    const int*   acq    = (const int*)d_in[1];
    const float* p0_w   = (const float*)d_in[2];
    const float* p0_b   = (const float*)d_in[3];
    const float* p1_w   = (const float*)d_in[4];
    const float* p1_b   = (const float*)d_in[5];
    const float* fc0_w  = (const float*)d_in[6];
    const float* fc0_b  = (const float*)d_in[7];
    const float* fc1_w  = (const float*)d_in[8];
    float* out = (float*)d_out;

    const size_t state_elems = (size_t)B * H * W * C;   // 16 MB each
    float* bufA = (float*)d_ws;
    float* bufB = bufA + state_elems;
    unsigned short* pack = (unsigned short*)(bufB + state_elems);  // 40 KB

    zero_acq0<<<B * T, 256, 0, stream>>>(acq, out);
    prep_pack<<<1, 256, 0, stream>>>(fc0_w, fc1_w, pack);

    const int n_cells = B * H * W;                 // 262144
    const dim3 grid(n_cells / 256), block(256);    // 1024 blocks, 4 tiles each

    const float* xin = inputs;
    for (int step = 0; step < NSTEPS; ++step) {
        float* xout = (step & 1) ? bufB : bufA;
        nca_step<<<grid, block, 0, stream>>>(
            xin, xout, p0_w, p0_b, p1_w, p1_b,
            pack, fc0_b, acq, out, step);
        xin = xout;
    }
}

// Round 9
// 2206.695 us; speedup vs baseline: 1.6106x; 1.6106x over previous
//
#include <hip/hip_runtime.h>
#include <hip/hip_bf16.h>

// NCA2D: B=16, H=128, W=128, C=16, T=8, HID=128, N_STEPS=64, FC0_IN=49
constexpr int B = 16, H = 128, W = 128, C = 16, T = 8, HID = 128, NSTEPS = 64;

using f32x4  = __attribute__((ext_vector_type(4))) float;
using bf16x8 = __attribute__((ext_vector_type(8))) short;

__device__ __forceinline__ unsigned short bf16_hi(float v) {
    __hip_bfloat16 h = __float2bfloat16(v);
    return *reinterpret_cast<unsigned short*>(&h);
}
__device__ __forceinline__ float bf16_f32(unsigned short u) {
    union { unsigned int u; float f; } c; c.u = ((unsigned int)u) << 16; return c.f;
}

// Packed fragment table (40 rows x 64 lanes x 16B = 40KB):
//  rows 0..31 : fc0 B-frags, row = nt*4 + f, f in {b0h,b0l,b1h,b1l}
//  rows 32..39: fc1 A-frags (W1), row = 32 + ks*2 + f, f in {hi,lo}
__global__ void prep_pack(const float* __restrict__ fc0_w, const float* __restrict__ fc1_w,
                          unsigned short* __restrict__ pack) {
    for (int e = threadIdx.x; e < 40 * 64; e += 256) {
        const int row = e >> 6, l = e & 63;
        const int m = l & 15, g = l >> 4;
        unsigned short v[8];
        if (row < 32) {
            const int nt = row >> 2, f = row & 3;
            const int n = nt * 16 + m;
            const int kbase = ((f >= 2) ? 32 : 0) + g * 8;
            #pragma unroll
            for (int j = 0; j < 8; ++j) {
                const int k = kbase + j;
                const float x = (k < 49) ? fc0_w[n * 49 + k] : 0.0f;
                const unsigned short hi = bf16_hi(x);
                v[j] = (f & 1) ? bf16_hi(x - bf16_f32(hi)) : hi;
            }
        } else {
            const int rr = row - 32, ks = rr >> 1, f = rr & 1;
            #pragma unroll
            for (int j = 0; j < 8; ++j) {
                const float x = fc1_w[m * HID + ks * 32 + g * 8 + j];
                const unsigned short hi = bf16_hi(x);
                v[j] = f ? bf16_hi(x - bf16_f32(hi)) : hi;
            }
        }
        #pragma unroll
        for (int j = 0; j < 8; ++j) pack[e * 8 + j] = v[j];
    }
}

// Zero only output slots whose acquire step is 0 (never snapshot-written).
__global__ void zero_acq0(const int* __restrict__ acq, float* __restrict__ out) {
    const int bt = blockIdx.x;
    if (acq[bt] != 0) return;
    float4* p = reinterpret_cast<float4*>(out + (size_t)bt * (H * W * C));
    for (int i = threadIdx.x; i < (H * W * C) / 4; i += 256)
        p[i] = make_float4(0.0f, 0.0f, 0.0f, 0.0f);
}

// Block = 4 rows x 64 cols of one image. Wave wv owns cols wv*16..+15 and walks
// 4 consecutive rows (tiles). Conv input rows overlap between tiles: only ONE
// new row (6 float4 = 24 VGPR) is loaded per tile, prefetched during the
// previous tile's MFMA phase. LDS 64KB -> 2 blocks/CU.
__global__ __launch_bounds__(256, 2) void nca_step(
    const float* __restrict__ x_in, float* __restrict__ x_out,
    const float* __restrict__ p0_w, const float* __restrict__ p0_b,
    const float* __restrict__ p1_w, const float* __restrict__ p1_b,
    const unsigned short* __restrict__ pack, const float* __restrict__ fc0_b,
    const int* __restrict__ acq, float* __restrict__ out, int step)
{
    __shared__ float wlds[32 * 256];   // fc0 B-frag rows
    __shared__ float hlds[4 * 2048];   // per-wave h[16][128], 16B-XOR swizzle

    const int tid  = threadIdx.x;
    const int wv   = tid >> 6;
    const int lane = tid & 63;
    const int m    = lane & 15;
    const int g    = lane >> 4;

    // ---- stage fc0 frag table global->LDS
    #pragma unroll
    for (int e0 = 0; e0 < 2048; e0 += 256) {
        const int e = e0 + tid;
        const int4 v = *reinterpret_cast<const int4*>(pack + (size_t)e * 8);
        *reinterpret_cast<int4*>(&wlds[e * 4]) = v;
    }

    const int bid = blockIdx.x;
    const int b   = bid >> 6;          // image (64 blocks per image)
    const int ib  = bid & 63;
    const int rb  = ib >> 1;           // row group (4 rows)
    const int c0  = (ib & 1) * 64 + wv * 16;
    const int wc  = c0 + m;            // this lane's column

    const float* pw = (g >= 2) ? p0_w : p1_w;
    const float* pb = (g >= 2) ? p0_b : p1_b;
    const int ch = (g & 1) * 8;
    float* hb = hlds + (wv << 11);
    const int lb = lane << 2;
    const int m7 = m & 7;
    const float prog = (float)step * (1.0f / (float)NSTEPS);
    const size_t imgbase = (size_t)b * (H * W);

    // ---- block-invariant loads
    int snapmask = 0;
    if (step > 0) {
        #pragma unroll
        for (int t = 0; t < T; ++t)
            snapmask |= (acq[b * T + t] == step) ? (1 << t) : 0;
    }
    bf16x8 w1f[8];
    #pragma unroll
    for (int q = 0; q < 8; ++q)
        w1f[q] = *reinterpret_cast<const bf16x8*>(pack + ((32 + q) * 64 + lane) * 8);
    float bias[8];
    #pragma unroll
    for (int nt = 0; nt < 8; ++nt) bias[nt] = fc0_b[nt * 16 + m];

    int ws[3];
    ws[0] = (wc == 0) ? 1 : wc - 1;  ws[1] = wc;  ws[2] = (wc == W - 1) ? W - 2 : wc + 1;

    // ---- conv row ring: rA (top), rB (mid), rC (bot); rN = prefetched next row
    const int r0 = rb * 4;
    float4 rA[3][2], rB[3][2], rC[3][2], rN[3][2];
    {
        const int rm1 = (r0 == 0) ? 1 : r0 - 1;
        #pragma unroll
        for (int j = 0; j < 3; ++j) {
            const float4* p = reinterpret_cast<const float4*>(
                x_in + ((imgbase + (size_t)rm1 * W + ws[j]) << 4) + ch);
            rA[j][0] = p[0]; rA[j][1] = p[1];
        }
        #pragma unroll
        for (int j = 0; j < 3; ++j) {
            const float4* p = reinterpret_cast<const float4*>(
                x_in + ((imgbase + (size_t)r0 * W + ws[j]) << 4) + ch);
            rB[j][0] = p[0]; rB[j][1] = p[1];
        }
        #pragma unroll
        for (int j = 0; j < 3; ++j) {
            const float4* p = reinterpret_cast<const float4*>(
                x_in + ((imgbase + (size_t)(r0 + 1) * W + ws[j]) << 4) + ch);
            rC[j][0] = p[0]; rC[j][1] = p[1];
        }
    }
    float4 xold4 = *reinterpret_cast<const float4*>(
        x_in + ((imgbase + (size_t)r0 * W + wc) << 4) + (g << 2));
    float4 xoldN;

    #pragma unroll
    for (int t = 0; t < 4; ++t) {
        const int r = r0 + t;

        // ---- conv FMAs from the register ring
        float z[8], xcen[8];
        #pragma unroll
        for (int j = 0; j < 8; ++j) z[j] = pb[ch + j];
        #pragma unroll
        for (int j = 0; j < 3; ++j) {
            const float4 qa = rA[j][0], qb = rA[j][1];
            const float xv[8] = {qa.x, qa.y, qa.z, qa.w, qb.x, qb.y, qb.z, qb.w};
            #pragma unroll
            for (int jj = 0; jj < 8; ++jj)
                z[jj] = fmaf(xv[jj], pw[j * 16 + ch + jj], z[jj]);
        }
        #pragma unroll
        for (int j = 0; j < 3; ++j) {
            const float4 qa = rB[j][0], qb = rB[j][1];
            const float xv[8] = {qa.x, qa.y, qa.z, qa.w, qb.x, qb.y, qb.z, qb.w};
            #pragma unroll
            for (int jj = 0; jj < 8; ++jj)
                z[jj] = fmaf(xv[jj], pw[(3 + j) * 16 + ch + jj], z[jj]);
        }
        #pragma unroll
        for (int j = 0; j < 3; ++j) {
            const float4 qa = rC[j][0], qb = rC[j][1];
            const float xv[8] = {qa.x, qa.y, qa.z, qa.w, qb.x, qb.y, qb.z, qb.w};
            #pragma unroll
            for (int jj = 0; jj < 8; ++jj)
                z[jj] = fmaf(xv[jj], pw[(6 + j) * 16 + ch + jj], z[jj]);
        }
        {
            const float4 qa = rB[1][0], qb = rB[1][1];
            xcen[0] = qa.x; xcen[1] = qa.y; xcen[2] = qa.z; xcen[3] = qa.w;
            xcen[4] = qb.x; xcen[5] = qb.y; xcen[6] = qb.z; xcen[7] = qb.w;
        }

        // ---- prefetch next tile's new bottom row + xold (hidden under MFMAs)
        if (t < 3) {
            int rt2 = r + 2; if (rt2 > H - 1) rt2 = H - 2;
            #pragma unroll
            for (int j = 0; j < 3; ++j) {
                const float4* p = reinterpret_cast<const float4*>(
                    x_in + ((imgbase + (size_t)rt2 * W + ws[j]) << 4) + ch);
                rN[j][0] = p[0]; rN[j][1] = p[1];
            }
            xoldN = *reinterpret_cast<const float4*>(
                x_in + ((imgbase + (size_t)(r + 1) * W + wc) << 4) + (g << 2));
        }

        // ---- A-frags (K=64: k0-31 = [x | z1], k32-63 = [z2 | prog | pad])
        bf16x8 a0h, a0l, a1h, a1l;
        #pragma unroll
        for (int j = 0; j < 8; ++j) {
            const float f0 = (g < 2) ? xcen[j] : z[j];
            const float f1 = (g < 2) ? z[j] : ((g == 2 && j == 0) ? prog : 0.0f);
            const unsigned short h0 = bf16_hi(f0);
            a0h[j] = (short)h0;  a0l[j] = (short)bf16_hi(f0 - bf16_f32(h0));
            const unsigned short h1 = bf16_hi(f1);
            a1h[j] = (short)h1;  a1l[j] = (short)bf16_hi(f1 - bf16_f32(h1));
        }

        if (t == 0) __syncthreads();   // staged wlds visible (uniform branch)

        // ---- fc0: h[16 cells][128 hid]; D: lane(g,m) reg r -> h[cell g*4+r][hid nt*16+m]
        #pragma unroll
        for (int nt = 0; nt < 8; ++nt) {
            const int rbo = nt << 10;
            const bf16x8 b0h = *reinterpret_cast<const bf16x8*>(&wlds[rbo + lb]);
            const bf16x8 b0l = *reinterpret_cast<const bf16x8*>(&wlds[rbo + 256 + lb]);
            const bf16x8 b1h = *reinterpret_cast<const bf16x8*>(&wlds[rbo + 512 + lb]);
            const bf16x8 b1l = *reinterpret_cast<const bf16x8*>(&wlds[rbo + 768 + lb]);
            f32x4 acc = {0.0f, 0.0f, 0.0f, 0.0f};
            acc = __builtin_amdgcn_mfma_f32_16x16x32_bf16(a0h, b0h, acc, 0, 0, 0);
            acc = __builtin_amdgcn_mfma_f32_16x16x32_bf16(a0l, b0h, acc, 0, 0, 0);
            acc = __builtin_amdgcn_mfma_f32_16x16x32_bf16(a0h, b0l, acc, 0, 0, 0);
            acc = __builtin_amdgcn_mfma_f32_16x16x32_bf16(a1h, b1h, acc, 0, 0, 0);
            acc = __builtin_amdgcn_mfma_f32_16x16x32_bf16(a1l, b1h, acc, 0, 0, 0);
            acc = __builtin_amdgcn_mfma_f32_16x16x32_bf16(a1h, b1l, acc, 0, 0, 0);
            const int hid4 = (nt << 2) + (m >> 2), ml = m & 3;
            #pragma unroll
            for (int rr = 0; rr < 4; ++rr) {
                const int cr = g * 4 + rr;
                hb[cr * 128 + (((hid4 ^ (cr & 7)) << 2) | ml)] = fmaxf(acc[rr] + bias[nt], 0.0f);
            }
        }
        // no block barrier: hlds is wave-private, within-wave DS ordering suffices

        // ---- fc1 swapped (D2 = W1 . h^T)
        f32x4 acc2 = {0.0f, 0.0f, 0.0f, 0.0f};
        #pragma unroll
        for (int ks = 0; ks < 4; ++ks) {
            const float4 h0 = *reinterpret_cast<const float4*>(
                &hb[m * 128 + ((((ks << 3) + (g << 1) + 0) ^ m7) << 2)]);
            const float4 h1 = *reinterpret_cast<const float4*>(
                &hb[m * 128 + ((((ks << 3) + (g << 1) + 1) ^ m7) << 2)]);
            const float hv[8] = {h0.x, h0.y, h0.z, h0.w, h1.x, h1.y, h1.z, h1.w};
            bf16x8 bh, bl;
            #pragma unroll
            for (int j = 0; j < 8; ++j) {
                const unsigned short hi = bf16_hi(hv[j]);
                bh[j] = (short)hi;
                bl[j] = (short)bf16_hi(hv[j] - bf16_f32(hi));
            }
            acc2 = __builtin_amdgcn_mfma_f32_16x16x32_bf16(w1f[ks * 2 + 0], bh, acc2, 0, 0, 0);
            acc2 = __builtin_amdgcn_mfma_f32_16x16x32_bf16(w1f[ks * 2 + 1], bh, acc2, 0, 0, 0);
            acc2 = __builtin_amdgcn_mfma_f32_16x16x32_bf16(w1f[ks * 2 + 0], bl, acc2, 0, 0, 0);
        }

        // ---- epilogue: lane(g,m) reg rr -> x[cell][ch g*4+rr]? no: D2 row=ch, col=cell
        const size_t cell = imgbase + (size_t)r * W + wc;
        float4 xn;
        xn.x = xold4.x + 1.0f / (1.0f + __expf(-acc2[0]));
        xn.y = xold4.y + 1.0f / (1.0f + __expf(-acc2[1]));
        xn.z = xold4.z + 1.0f / (1.0f + __expf(-acc2[2]));
        xn.w = xold4.w + 1.0f / (1.0f + __expf(-acc2[3]));
        *reinterpret_cast<float4*>(x_out + (cell << 4) + (g << 2)) = xn;
        if (snapmask) {
            #pragma unroll
            for (int tt = 0; tt < T; ++tt) {
                if (snapmask & (1 << tt)) {
                    *reinterpret_cast<float4*>(out + (size_t)(b * T + tt) * (H * W * C)
                        + (((size_t)r * W + wc) << 4) + (g << 2)) = xn;
                }
            }
        }

        // ---- ring shift (static indices, ~24 v_movs)
        if (t < 3) {
            #pragma unroll
            for (int j = 0; j < 3; ++j) {
                rA[j][0] = rB[j][0]; rA[j][1] = rB[j][1];
                rB[j][0] = rC[j][0]; rB[j][1] = rC[j][1];
                rC[j][0] = rN[j][0]; rC[j][1] = rN[j][1];
            }
            xold4 = xoldN;
        }
    }
}

extern "C" void kernel_launch(void* const* d_in, const int* in_sizes, int n_in,
                              void* d_out, int out_size, void* d_ws, size_t ws_size,
                              hipStream_t stream) {
    const float* inputs = (const float*)d_in[0];
    const int*   acq    = (const int*)d_in[1];
    const float* p0_w   = (const float*)d_in[2];
    const float* p0_b   = (const float*)d_in[3];
    const float* p1_w   = (const float*)d_in[4];
    const float* p1_b   = (const float*)d_in[5];
    const float* fc0_w  = (const float*)d_in[6];
    const float* fc0_b  = (const float*)d_in[7];
    const float* fc1_w  = (const float*)d_in[8];
    float* out = (float*)d_out;

    const size_t state_elems = (size_t)B * H * W * C;   // 16 MB each
    float* bufA = (float*)d_ws;
    float* bufB = bufA + state_elems;
    unsigned short* pack = (unsigned short*)(bufB + state_elems);  // 40 KB

    zero_acq0<<<B * T, 256, 0, stream>>>(acq, out);
    prep_pack<<<1, 256, 0, stream>>>(fc0_w, fc1_w, pack);

    const int n_cells = B * H * W;                 // 262144
    const dim3 grid(n_cells / 256), block(256);    // 1024 blocks: 4 rows x 64 cols

    const float* xin = inputs;
    for (int step = 0; step < NSTEPS; ++step) {
        float* xout = (step & 1) ? bufB : bufA;
        nca_step<<<grid, block, 0, stream>>>(
            xin, xout, p0_w, p0_b, p1_w, p1_b,
            pack, fc0_b, acq, out, step);
        xin = xout;
    }
}